// Round 3
// baseline (287.646 us; speedup 1.0000x reference)
//
#include <hip/hip_runtime.h>
#include <hip/hip_fp16.h>

#define D 256

typedef __attribute__((ext_vector_type(4))) _Float16 half4;

// ---------------- graph build ----------------

__global__ void count_deg(const int* __restrict__ dst, int E, int* __restrict__ cnt) {
    int e = blockIdx.x * blockDim.x + threadIdx.x;
    if (e < E) atomicAdd(&cnt[dst[e]], 1);
}

// single block, 1024 threads: exclusive scan of cnt -> row_ofs/cursor, dinv = rsqrt(cnt+1)
__global__ void scan_build(const int* __restrict__ cnt, int* __restrict__ row_ofs,
                           int* __restrict__ cursor, float* __restrict__ dinv, int n) {
    __shared__ int part[1024];
    int t = threadIdx.x;
    int CH = (n + 1023) >> 10;
    int base = t * CH;
    int sum = 0;
    for (int i = 0; i < CH; i++) { int idx = base + i; if (idx < n) sum += cnt[idx]; }
    part[t] = sum;
    __syncthreads();
    for (int off = 1; off < 1024; off <<= 1) {
        int v = (t >= off) ? part[t - off] : 0;
        __syncthreads();
        part[t] += v;
        __syncthreads();
    }
    int prefix = t ? part[t - 1] : 0;
    for (int i = 0; i < CH; i++) {
        int idx = base + i;
        if (idx < n) {
            int c = cnt[idx];
            row_ofs[idx] = prefix;
            cursor[idx] = prefix;
            dinv[idx] = rsqrtf((float)(c + 1));  // +1 = self loop
            prefix += c;
        }
    }
    if (t == 1023) row_ofs[n] = part[1023];
}

__global__ void fill_csr(const int* __restrict__ src, const int* __restrict__ dst, int E,
                         int* __restrict__ cursor, int* __restrict__ csr_src) {
    int e = blockIdx.x * blockDim.x + threadIdx.x;
    if (e < E) {
        int d = dst[e];
        int pos = atomicAdd(&cursor[d], 1);
        csr_src[pos] = src[e];
    }
}

// ---------------- fp32 GEMM: C[M,256] = A[M,256] x B[256,256], fp16 store ----------------
// 64x64 tile / block(256), 4x4 register micro-tile, K staged 16-deep in LDS.
// No fp32-input MFMA on CDNA4 -> vector ALU. Accumulate fp32, round once to fp16.
__global__ void gemm_f32h(const float* __restrict__ A, const float* __restrict__ B,
                          _Float16* __restrict__ C, int M) {
    __shared__ float As[16][64];  // As[k][m]
    __shared__ float Bs[16][64];  // Bs[k][n]
    int t = threadIdx.x;
    int tx = t & 15, ty = t >> 4;
    int m0 = blockIdx.x << 6;
    int n0 = blockIdx.y << 6;
    int ar = t >> 2;             // 0..63 tile row
    int ak = (t & 3) << 2;       // k offset (float4)
    int br = t >> 4;             // 0..15 k row
    int bc = (t & 15) << 2;      // col offset (float4)
    int arow = m0 + ar;
    if (arow >= M) arow = M - 1;
    float acc[4][4] = {};
    for (int k0 = 0; k0 < D; k0 += 16) {
        float4 av = *(const float4*)(A + (size_t)arow * D + k0 + ak);
        float4 bv = *(const float4*)(B + (size_t)(k0 + br) * D + n0 + bc);
        __syncthreads();  // previous iteration's reads done
        As[ak + 0][ar] = av.x;
        As[ak + 1][ar] = av.y;
        As[ak + 2][ar] = av.z;
        As[ak + 3][ar] = av.w;
        *(float4*)(&Bs[br][bc]) = bv;
        __syncthreads();
#pragma unroll
        for (int kk = 0; kk < 16; kk++) {
            float4 a = *(const float4*)(&As[kk][ty << 2]);
            float4 b = *(const float4*)(&Bs[kk][tx << 2]);
            acc[0][0] += a.x * b.x; acc[0][1] += a.x * b.y; acc[0][2] += a.x * b.z; acc[0][3] += a.x * b.w;
            acc[1][0] += a.y * b.x; acc[1][1] += a.y * b.y; acc[1][2] += a.y * b.z; acc[1][3] += a.y * b.w;
            acc[2][0] += a.z * b.x; acc[2][1] += a.z * b.y; acc[2][2] += a.z * b.z; acc[2][3] += a.z * b.w;
            acc[3][0] += a.w * b.x; acc[3][1] += a.w * b.y; acc[3][2] += a.w * b.z; acc[3][3] += a.w * b.w;
        }
    }
#pragma unroll
    for (int i = 0; i < 4; i++) {
        int m = m0 + (ty << 2) + i;
        if (m < M) {
            half4 v = {(_Float16)acc[i][0], (_Float16)acc[i][1],
                       (_Float16)acc[i][2], (_Float16)acc[i][3]};
            *(half4*)(C + (size_t)m * D + n0 + (tx << 2)) = v;
        }
    }
}

// ---------------- GCN aggregate (fused bias+relu), fp16 gathers ----------------
// one wave per node; lane owns dims [4*lane, 4*lane+4)
__global__ void gcn_agg(const _Float16* __restrict__ xw1, const int* __restrict__ csr,
                        const int* __restrict__ row_ofs, const float* __restrict__ dinv,
                        const float* __restrict__ b1, float* __restrict__ x1, int n) {
    int node = (blockIdx.x << 2) + (threadIdx.x >> 6);
    if (node >= n) return;
    int lane = threadIdx.x & 63;
    float dd = dinv[node];
    half4 v = ((const half4*)(xw1 + (size_t)node * D))[lane];
    float w = dd * dd;  // self loop norm
    float a0 = (float)v[0] * w, a1 = (float)v[1] * w, a2 = (float)v[2] * w, a3 = (float)v[3] * w;
    int beg = row_ofs[node], end = row_ofs[node + 1];
    for (int e = beg; e < end; e++) {
        int s = csr[e];
        float ws = dinv[s] * dd;
        half4 u = ((const half4*)(xw1 + (size_t)s * D))[lane];
        a0 += (float)u[0] * ws; a1 += (float)u[1] * ws;
        a2 += (float)u[2] * ws; a3 += (float)u[3] * ws;
    }
    int c = lane * 4;
    float4 bb = *(const float4*)(b1 + c);
    a0 += bb.x; a1 += bb.y; a2 += bb.z; a3 += bb.w;
    a0 = a0 > 0.f ? a0 : 0.f;
    a1 = a1 > 0.f ? a1 : 0.f;
    a2 = a2 > 0.f ? a2 : 0.f;
    a3 = a3 > 0.f ? a3 : 0.f;
    *(float4*)(x1 + (size_t)node * D + c) = make_float4(a0, a1, a2, a3);
}

// ---------------- per-node attention dot products (fp16 xw2) ----------------
__global__ void att_dots(const _Float16* __restrict__ xw2, const float* __restrict__ att_s,
                         const float* __restrict__ att_d, float* __restrict__ asrc,
                         float* __restrict__ adst, int n) {
    int node = (blockIdx.x << 2) + (threadIdx.x >> 6);
    if (node >= n) return;
    int lane = threadIdx.x & 63;
    half4 v = ((const half4*)(xw2 + (size_t)node * D))[lane];
    int c = lane * 4;
    float4 as = *(const float4*)(att_s + c);
    float4 ad = *(const float4*)(att_d + c);
    float s1 = (float)v[0] * as.x + (float)v[1] * as.y + (float)v[2] * as.z + (float)v[3] * as.w;
    float s2 = (float)v[0] * ad.x + (float)v[1] * ad.y + (float)v[2] * ad.z + (float)v[3] * ad.w;
    for (int off = 32; off > 0; off >>= 1) {
        s1 += __shfl_down(s1, off);
        s2 += __shfl_down(s2, off);
    }
    if (lane == 0) { asrc[node] = s1; adst[node] = s2; }
}

// ---------------- GAT aggregate: online softmax, fused bias+relu, fp16 gathers ----------------
__global__ void gat_agg(const _Float16* __restrict__ xw2, const int* __restrict__ csr,
                        const int* __restrict__ row_ofs, const float* __restrict__ asrc,
                        const float* __restrict__ adst, const float* __restrict__ b2,
                        float* __restrict__ out, int n) {
    int node = (blockIdx.x << 2) + (threadIdx.x >> 6);
    if (node >= n) return;
    int lane = threadIdx.x & 63;
    float ad = adst[node];
    float e_self = asrc[node] + ad;
    e_self = e_self > 0.f ? e_self : 0.2f * e_self;
    float m = e_self, ssum = 1.0f;
    half4 v = ((const half4*)(xw2 + (size_t)node * D))[lane];
    float a0 = (float)v[0], a1 = (float)v[1], a2 = (float)v[2], a3 = (float)v[3];  // self, exp(0)=1
    int beg = row_ofs[node], end = row_ofs[node + 1];
    for (int e = beg; e < end; e++) {
        int s = csr[e];
        float ev = asrc[s] + ad;
        ev = ev > 0.f ? ev : 0.2f * ev;
        half4 u = ((const half4*)(xw2 + (size_t)s * D))[lane];
        float u0 = (float)u[0], u1 = (float)u[1], u2 = (float)u[2], u3 = (float)u[3];
        if (ev <= m) {
            float w = __expf(ev - m);
            ssum += w;
            a0 += u0 * w; a1 += u1 * w; a2 += u2 * w; a3 += u3 * w;
        } else {
            float f = __expf(m - ev);
            ssum = ssum * f + 1.0f;
            a0 = a0 * f + u0; a1 = a1 * f + u1; a2 = a2 * f + u2; a3 = a3 * f + u3;
            m = ev;
        }
    }
    float inv = 1.0f / (ssum + 1e-16f);
    int c = lane * 4;
    float4 bb = *(const float4*)(b2 + c);
    float r0 = a0 * inv + bb.x;
    float r1 = a1 * inv + bb.y;
    float r2 = a2 * inv + bb.z;
    float r3 = a3 * inv + bb.w;
    r0 = r0 > 0.f ? r0 : 0.f;
    r1 = r1 > 0.f ? r1 : 0.f;
    r2 = r2 > 0.f ? r2 : 0.f;
    r3 = r3 > 0.f ? r3 : 0.f;
    *(float4*)(out + (size_t)node * D + c) = make_float4(r0, r1, r2, r3);
}

// ---------------- launch ----------------

extern "C" void kernel_launch(void* const* d_in, const int* in_sizes, int n_in,
                              void* d_out, int out_size, void* d_ws, size_t ws_size,
                              hipStream_t stream) {
    const float* emb = (const float*)d_in[0];  // [N,256] f32
    const int*   ei  = (const int*)d_in[1];    // [2,E] int32
    const float* W1  = (const float*)d_in[2];  // [256,256] f32
    const float* b1  = (const float*)d_in[3];  // [256]
    const float* W2  = (const float*)d_in[4];  // [256,256] f32
    const float* atS = (const float*)d_in[5];  // [256]
    const float* atD = (const float*)d_in[6];  // [256]
    const float* b2  = (const float*)d_in[7];  // [256]

    int n = in_sizes[0] / D;  // 10000
    int E = in_sizes[1] / 2;  // 320000
    const int* src = ei;
    const int* dst = ei + E;

    char* w = (char*)d_ws;
    auto alloc = [&](size_t bytes) -> char* {
        char* p = w;
        w += (bytes + 255) & ~(size_t)255;
        return p;
    };
    int*      cnt     = (int*)alloc((size_t)n * 4);
    int*      row_ofs = (int*)alloc((size_t)(n + 1) * 4);
    int*      cursor  = (int*)alloc((size_t)n * 4);
    float*    dinv    = (float*)alloc((size_t)n * 4);
    int*      csr     = (int*)alloc((size_t)E * 4);
    _Float16* xw1h    = (_Float16*)alloc((size_t)n * D * 2);
    float*    x1      = (float*)alloc((size_t)n * D * 4);
    float*    asrc    = (float*)alloc((size_t)n * 4);
    float*    adst    = (float*)alloc((size_t)n * 4);
    _Float16* xw2h    = xw1h;  // xw1h dead after gcn_agg

    hipMemsetAsync(cnt, 0, (size_t)n * 4, stream);
    int eb = (E + 255) / 256;
    count_deg<<<eb, 256, 0, stream>>>(dst, E, cnt);
    scan_build<<<1, 1024, 0, stream>>>(cnt, row_ofs, cursor, dinv, n);
    fill_csr<<<eb, 256, 0, stream>>>(src, dst, E, cursor, csr);

    dim3 ggrid((n + 63) / 64, 4);
    gemm_f32h<<<ggrid, 256, 0, stream>>>(emb, W1, xw1h, n);

    int nb = (n + 3) / 4;
    gcn_agg<<<nb, 256, 0, stream>>>(xw1h, csr, row_ofs, dinv, b1, x1, n);

    gemm_f32h<<<ggrid, 256, 0, stream>>>(x1, W2, xw2h, n);
    att_dots<<<nb, 256, 0, stream>>>(xw2h, atS, atD, asrc, adst, n);
    gat_agg<<<nb, 256, 0, stream>>>(xw2h, csr, row_ofs, asrc, adst, b2, (float*)d_out, n);
}

// Round 4
// 249.379 us; speedup vs baseline: 1.1534x; 1.1534x over previous
//
#include <hip/hip_runtime.h>
#include <hip/hip_fp16.h>

#define D 256
#define UN 8

typedef __attribute__((ext_vector_type(4))) _Float16 half4;

// ---------------- graph build ----------------

__global__ void count_deg(const int* __restrict__ dst, int E, int* __restrict__ cnt) {
    int e = blockIdx.x * blockDim.x + threadIdx.x;
    if (e < E) atomicAdd(&cnt[dst[e]], 1);
}

// single block, 1024 threads: exclusive scan of cnt -> row_ofs/cursor, dinv = rsqrt(cnt+1)
__global__ void scan_build(const int* __restrict__ cnt, int* __restrict__ row_ofs,
                           int* __restrict__ cursor, float* __restrict__ dinv, int n) {
    __shared__ int part[1024];
    int t = threadIdx.x;
    int CH = (n + 1023) >> 10;
    int base = t * CH;
    int sum = 0;
    for (int i = 0; i < CH; i++) { int idx = base + i; if (idx < n) sum += cnt[idx]; }
    part[t] = sum;
    __syncthreads();
    for (int off = 1; off < 1024; off <<= 1) {
        int v = (t >= off) ? part[t - off] : 0;
        __syncthreads();
        part[t] += v;
        __syncthreads();
    }
    int prefix = t ? part[t - 1] : 0;
    for (int i = 0; i < CH; i++) {
        int idx = base + i;
        if (idx < n) {
            int c = cnt[idx];
            row_ofs[idx] = prefix;
            cursor[idx] = prefix;
            dinv[idx] = rsqrtf((float)(c + 1));  // +1 = self loop
            prefix += c;
        }
    }
    if (t == 1023) row_ofs[n] = part[1023];
}

__global__ void fill_csr(const int* __restrict__ src, const int* __restrict__ dst, int E,
                         int* __restrict__ cursor, int* __restrict__ csr_src) {
    int e = blockIdx.x * blockDim.x + threadIdx.x;
    if (e < E) {
        int d = dst[e];
        int pos = atomicAdd(&cursor[d], 1);
        csr_src[pos] = src[e];
    }
}

// ---------------- fp32 GEMM: C[M,256] = A[M,256] x B[256,256], fp16 store ----------------
__global__ void gemm_f32h(const float* __restrict__ A, const float* __restrict__ B,
                          _Float16* __restrict__ C, int M) {
    __shared__ float As[16][64];  // As[k][m]
    __shared__ float Bs[16][64];  // Bs[k][n]
    int t = threadIdx.x;
    int tx = t & 15, ty = t >> 4;
    int m0 = blockIdx.x << 6;
    int n0 = blockIdx.y << 6;
    int ar = t >> 2;
    int ak = (t & 3) << 2;
    int br = t >> 4;
    int bc = (t & 15) << 2;
    int arow = m0 + ar;
    if (arow >= M) arow = M - 1;
    float acc[4][4] = {};
    for (int k0 = 0; k0 < D; k0 += 16) {
        float4 av = *(const float4*)(A + (size_t)arow * D + k0 + ak);
        float4 bv = *(const float4*)(B + (size_t)(k0 + br) * D + n0 + bc);
        __syncthreads();
        As[ak + 0][ar] = av.x;
        As[ak + 1][ar] = av.y;
        As[ak + 2][ar] = av.z;
        As[ak + 3][ar] = av.w;
        *(float4*)(&Bs[br][bc]) = bv;
        __syncthreads();
#pragma unroll
        for (int kk = 0; kk < 16; kk++) {
            float4 a = *(const float4*)(&As[kk][ty << 2]);
            float4 b = *(const float4*)(&Bs[kk][tx << 2]);
            acc[0][0] += a.x * b.x; acc[0][1] += a.x * b.y; acc[0][2] += a.x * b.z; acc[0][3] += a.x * b.w;
            acc[1][0] += a.y * b.x; acc[1][1] += a.y * b.y; acc[1][2] += a.y * b.z; acc[1][3] += a.y * b.w;
            acc[2][0] += a.z * b.x; acc[2][1] += a.z * b.y; acc[2][2] += a.z * b.z; acc[2][3] += a.z * b.w;
            acc[3][0] += a.w * b.x; acc[3][1] += a.w * b.y; acc[3][2] += a.w * b.z; acc[3][3] += a.w * b.w;
        }
    }
#pragma unroll
    for (int i = 0; i < 4; i++) {
        int m = m0 + (ty << 2) + i;
        if (m < M) {
            half4 v = {(_Float16)acc[i][0], (_Float16)acc[i][1],
                       (_Float16)acc[i][2], (_Float16)acc[i][3]};
            *(half4*)(C + (size_t)m * D + n0 + (tx << 2)) = v;
        }
    }
}

// ---------------- GCN aggregate: 8-way unrolled gather, fused bias+relu ----------------
// one wave per node; lane owns dims [4*lane, 4*lane+4)
__global__ void gcn_agg(const _Float16* __restrict__ xw1, const int* __restrict__ csr,
                        const int* __restrict__ row_ofs, const float* __restrict__ dinv,
                        const float* __restrict__ b1, float* __restrict__ x1, int n) {
    int node = (blockIdx.x << 2) + (threadIdx.x >> 6);
    if (node >= n) return;
    int lane = threadIdx.x & 63;
    float dd = dinv[node];
    float ax[UN][4];
#pragma unroll
    for (int j = 0; j < UN; j++) { ax[j][0] = ax[j][1] = ax[j][2] = ax[j][3] = 0.f; }
    {   // self loop
        half4 v = ((const half4*)(xw1 + (size_t)node * D))[lane];
        float w = dd * dd;
        ax[0][0] = (float)v[0] * w; ax[0][1] = (float)v[1] * w;
        ax[0][2] = (float)v[2] * w; ax[0][3] = (float)v[3] * w;
    }
    int beg = row_ofs[node], end = row_ofs[node + 1];
    int e = beg;
    for (; e + UN <= end; e += UN) {
        int s[UN];
#pragma unroll
        for (int j = 0; j < UN; j++) s[j] = csr[e + j];
#pragma unroll
        for (int j = 0; j < UN; j++) {
            float ws = dinv[s[j]] * dd;
            half4 u = ((const half4*)(xw1 + (size_t)s[j] * D))[lane];
            ax[j][0] += (float)u[0] * ws; ax[j][1] += (float)u[1] * ws;
            ax[j][2] += (float)u[2] * ws; ax[j][3] += (float)u[3] * ws;
        }
    }
    for (; e < end; e++) {
        int s = csr[e];
        float ws = dinv[s] * dd;
        half4 u = ((const half4*)(xw1 + (size_t)s * D))[lane];
        ax[0][0] += (float)u[0] * ws; ax[0][1] += (float)u[1] * ws;
        ax[0][2] += (float)u[2] * ws; ax[0][3] += (float)u[3] * ws;
    }
    float a0 = 0.f, a1 = 0.f, a2 = 0.f, a3 = 0.f;
#pragma unroll
    for (int j = 0; j < UN; j++) { a0 += ax[j][0]; a1 += ax[j][1]; a2 += ax[j][2]; a3 += ax[j][3]; }
    int c = lane * 4;
    float4 bb = *(const float4*)(b1 + c);
    a0 += bb.x; a1 += bb.y; a2 += bb.z; a3 += bb.w;
    a0 = a0 > 0.f ? a0 : 0.f;
    a1 = a1 > 0.f ? a1 : 0.f;
    a2 = a2 > 0.f ? a2 : 0.f;
    a3 = a3 > 0.f ? a3 : 0.f;
    *(float4*)(x1 + (size_t)node * D + c) = make_float4(a0, a1, a2, a3);
}

// ---------------- per-node attention dot products (fp16 xw2) ----------------
__global__ void att_dots(const _Float16* __restrict__ xw2, const float* __restrict__ att_s,
                         const float* __restrict__ att_d, float* __restrict__ asrc,
                         float* __restrict__ adst, int n) {
    int node = (blockIdx.x << 2) + (threadIdx.x >> 6);
    if (node >= n) return;
    int lane = threadIdx.x & 63;
    half4 v = ((const half4*)(xw2 + (size_t)node * D))[lane];
    int c = lane * 4;
    float4 as = *(const float4*)(att_s + c);
    float4 ad = *(const float4*)(att_d + c);
    float s1 = (float)v[0] * as.x + (float)v[1] * as.y + (float)v[2] * as.z + (float)v[3] * as.w;
    float s2 = (float)v[0] * ad.x + (float)v[1] * ad.y + (float)v[2] * ad.z + (float)v[3] * ad.w;
    for (int off = 32; off > 0; off >>= 1) {
        s1 += __shfl_down(s1, off);
        s2 += __shfl_down(s2, off);
    }
    if (lane == 0) { asrc[node] = s1; adst[node] = s2; }
}

// ---------------- GAT aggregate: two-pass softmax (max then weighted sum), 8-way MLP ----------------
__global__ void gat_agg(const _Float16* __restrict__ xw2, const int* __restrict__ csr,
                        const int* __restrict__ row_ofs, const float* __restrict__ asrc,
                        const float* __restrict__ adst, const float* __restrict__ b2,
                        float* __restrict__ out, int n) {
    int node = (blockIdx.x << 2) + (threadIdx.x >> 6);
    if (node >= n) return;
    int lane = threadIdx.x & 63;
    float ad = adst[node];
    float e_self = asrc[node] + ad;
    e_self = e_self > 0.f ? e_self : 0.2f * e_self;
    int beg = row_ofs[node], end = row_ofs[node + 1];

    // ---- pass 1: true max of edge logits ----
    float m = e_self;
    int e = beg;
    for (; e + UN <= end; e += UN) {
        int s[UN];
#pragma unroll
        for (int j = 0; j < UN; j++) s[j] = csr[e + j];
        float mm[UN];
#pragma unroll
        for (int j = 0; j < UN; j++) {
            float ev = asrc[s[j]] + ad;
            mm[j] = ev > 0.f ? ev : 0.2f * ev;
        }
#pragma unroll
        for (int j = 0; j < UN; j++) m = m > mm[j] ? m : mm[j];
    }
    for (; e < end; e++) {
        int s = csr[e];
        float ev = asrc[s] + ad;
        ev = ev > 0.f ? ev : 0.2f * ev;
        m = m > ev ? m : ev;
    }

    // ---- pass 2: weighted sum with fixed m (no serial rescale) ----
    float ax[UN][4];
    float ps[UN];
#pragma unroll
    for (int j = 0; j < UN; j++) { ax[j][0] = ax[j][1] = ax[j][2] = ax[j][3] = 0.f; ps[j] = 0.f; }
    {   // self loop
        float w = __expf(e_self - m);
        half4 v = ((const half4*)(xw2 + (size_t)node * D))[lane];
        ax[0][0] = (float)v[0] * w; ax[0][1] = (float)v[1] * w;
        ax[0][2] = (float)v[2] * w; ax[0][3] = (float)v[3] * w;
        ps[0] = w;
    }
    e = beg;
    for (; e + UN <= end; e += UN) {
        int s[UN];
#pragma unroll
        for (int j = 0; j < UN; j++) s[j] = csr[e + j];
#pragma unroll
        for (int j = 0; j < UN; j++) {
            float ev = asrc[s[j]] + ad;
            ev = ev > 0.f ? ev : 0.2f * ev;
            float w = __expf(ev - m);
            half4 u = ((const half4*)(xw2 + (size_t)s[j] * D))[lane];
            ps[j] += w;
            ax[j][0] += (float)u[0] * w; ax[j][1] += (float)u[1] * w;
            ax[j][2] += (float)u[2] * w; ax[j][3] += (float)u[3] * w;
        }
    }
    for (; e < end; e++) {
        int s = csr[e];
        float ev = asrc[s] + ad;
        ev = ev > 0.f ? ev : 0.2f * ev;
        float w = __expf(ev - m);
        half4 u = ((const half4*)(xw2 + (size_t)s * D))[lane];
        ps[0] += w;
        ax[0][0] += (float)u[0] * w; ax[0][1] += (float)u[1] * w;
        ax[0][2] += (float)u[2] * w; ax[0][3] += (float)u[3] * w;
    }
    float a0 = 0.f, a1 = 0.f, a2 = 0.f, a3 = 0.f, ssum = 0.f;
#pragma unroll
    for (int j = 0; j < UN; j++) {
        a0 += ax[j][0]; a1 += ax[j][1]; a2 += ax[j][2]; a3 += ax[j][3]; ssum += ps[j];
    }
    float inv = 1.0f / (ssum + 1e-16f);
    int c = lane * 4;
    float4 bb = *(const float4*)(b2 + c);
    float r0 = a0 * inv + bb.x;
    float r1 = a1 * inv + bb.y;
    float r2 = a2 * inv + bb.z;
    float r3 = a3 * inv + bb.w;
    r0 = r0 > 0.f ? r0 : 0.f;
    r1 = r1 > 0.f ? r1 : 0.f;
    r2 = r2 > 0.f ? r2 : 0.f;
    r3 = r3 > 0.f ? r3 : 0.f;
    *(float4*)(out + (size_t)node * D + c) = make_float4(r0, r1, r2, r3);
}

// ---------------- launch ----------------

extern "C" void kernel_launch(void* const* d_in, const int* in_sizes, int n_in,
                              void* d_out, int out_size, void* d_ws, size_t ws_size,
                              hipStream_t stream) {
    const float* emb = (const float*)d_in[0];  // [N,256] f32
    const int*   ei  = (const int*)d_in[1];    // [2,E] int32
    const float* W1  = (const float*)d_in[2];  // [256,256] f32
    const float* b1  = (const float*)d_in[3];  // [256]
    const float* W2  = (const float*)d_in[4];  // [256,256] f32
    const float* atS = (const float*)d_in[5];  // [256]
    const float* atD = (const float*)d_in[6];  // [256]
    const float* b2  = (const float*)d_in[7];  // [256]

    int n = in_sizes[0] / D;  // 10000
    int E = in_sizes[1] / 2;  // 320000
    const int* src = ei;
    const int* dst = ei + E;

    char* w = (char*)d_ws;
    auto alloc = [&](size_t bytes) -> char* {
        char* p = w;
        w += (bytes + 255) & ~(size_t)255;
        return p;
    };
    int*      cnt     = (int*)alloc((size_t)n * 4);
    int*      row_ofs = (int*)alloc((size_t)(n + 1) * 4);
    int*      cursor  = (int*)alloc((size_t)n * 4);
    float*    dinv    = (float*)alloc((size_t)n * 4);
    int*      csr     = (int*)alloc((size_t)E * 4);
    _Float16* xw1h    = (_Float16*)alloc((size_t)n * D * 2);
    float*    x1      = (float*)alloc((size_t)n * D * 4);
    float*    asrc    = (float*)alloc((size_t)n * 4);
    float*    adst    = (float*)alloc((size_t)n * 4);
    _Float16* xw2h    = xw1h;  // xw1h dead after gcn_agg

    hipMemsetAsync(cnt, 0, (size_t)n * 4, stream);
    int eb = (E + 255) / 256;
    count_deg<<<eb, 256, 0, stream>>>(dst, E, cnt);
    scan_build<<<1, 1024, 0, stream>>>(cnt, row_ofs, cursor, dinv, n);
    fill_csr<<<eb, 256, 0, stream>>>(src, dst, E, cursor, csr);

    dim3 ggrid((n + 63) / 64, 4);
    gemm_f32h<<<ggrid, 256, 0, stream>>>(emb, W1, xw1h, n);

    int nb = (n + 3) / 4;
    gcn_agg<<<nb, 256, 0, stream>>>(xw1h, csr, row_ofs, dinv, b1, x1, n);

    gemm_f32h<<<ggrid, 256, 0, stream>>>(x1, W2, xw2h, n);
    att_dots<<<nb, 256, 0, stream>>>(xw2h, atS, atD, asrc, adst, n);
    gat_agg<<<nb, 256, 0, stream>>>(xw2h, csr, row_ofs, asrc, adst, b2, (float*)d_out, n);
}